// Round 2
// baseline (215.265 us; speedup 1.0000x reference)
//
#include <hip/hip_runtime.h>
#include <hip/hip_bf16.h>

#define NMODELS 64
#define BBATCH  4096
#define IN_DIM  64
#define H_DIM   256

typedef __attribute__((ext_vector_type(8))) short short8;
typedef __attribute__((ext_vector_type(4))) float floatx4;
typedef __attribute__((ext_vector_type(4))) unsigned int uint4v;
typedef __attribute__((ext_vector_type(2))) unsigned int uint2v;

__device__ __forceinline__ unsigned short f2bf(float f) {   // prep only
    unsigned int u = __builtin_bit_cast(unsigned int, f);
    return (unsigned short)((u + 0x8000u) >> 16);
}
// packed fp32x2 -> bf16x2 (v_cvt_pk_bf16_f32 on gfx950), RNE
__device__ __forceinline__ unsigned int pkbf(float a, float b) {
    __hip_bfloat162 h = __float22bfloat162_rn(make_float2(a, b));
    unsigned int u;
    __builtin_memcpy(&u, &h, 4);
    return u;
}

// Transpose+cvt: W1 [M][64][256]->w1t [M][256][64] bf16 (blocks 0..255)
//                W2 [M][256][256]->w2t [M][256][256] bf16 (blocks 256..1279)
__global__ __launch_bounds__(256) void prep_weights(const float* __restrict__ W1,
                                                    const float* __restrict__ W2,
                                                    unsigned short* __restrict__ w1t,
                                                    unsigned short* __restrict__ w2t) {
    __shared__ float lds[64][65];
    const int bid = blockIdx.x;
    const float* src;
    unsigned short* dst;
    int K, N, m, kb, nb;
    if (bid < 256) {
        m = bid >> 2; kb = 0; nb = bid & 3; K = IN_DIM; N = H_DIM;
        src = W1; dst = w1t;
    } else {
        int t = bid - 256;
        m = t >> 4; kb = (t >> 2) & 3; nb = t & 3; K = H_DIM; N = H_DIM;
        src = W2; dst = w2t;
    }
    const float* s = src + ((size_t)m * K + (size_t)kb * 64) * N + nb * 64;
    const int tid = threadIdx.x;
    const int r = tid >> 4, c4 = (tid & 15) * 4;
#pragma unroll
    for (int p = 0; p < 4; ++p) {
        int row = p * 16 + r;                      // k-local 0..63
        float4 v = *(const float4*)(s + (size_t)row * N + c4);
        lds[row][c4] = v.x; lds[row][c4 + 1] = v.y;
        lds[row][c4 + 2] = v.z; lds[row][c4 + 3] = v.w;
    }
    __syncthreads();
    unsigned short* dbase = dst + ((size_t)m * N + (size_t)nb * 64) * K + kb * 64;
    const int j = tid & 7;                         // k-chunk 0..7
#pragma unroll
    for (int it = 0; it < 2; ++it) {
        int n = it * 32 + (tid >> 3);              // n-local 0..63
        unsigned short tmp[8];
#pragma unroll
        for (int e = 0; e < 8; ++e) tmp[e] = f2bf(lds[j * 8 + e][n]);
        *(short8*)(dbase + (size_t)n * K + j * 8) = *(const short8*)tmp;
    }
}

// Fused 3-layer MLP, T=1 batch tile per WG (occupancy-first restructure).
// Previous T=2 version: 64 KB LDS + ~244 unified regs -> 2 WG/CU, 21.7% occ,
// MfmaUtil 16.7 (latency-bound). T=1 halves LDS (32 KB) and regs
// (acc 64 AGPR + ax 32 + bv 32 ping-pong + misc ~ 155) -> 3 WG/CU via
// __launch_bounds__(256,3). W2 B-frags reused across 1 tile instead of 2:
// L2-side W2 traffic 256->512 MB (~15 us of 34.5 TB/s aggregate, affordable);
// HBM traffic unchanged (W2 is L2-resident, 128 KB/model).
// Wave w owns h-cols {w*64 + c16*4 + nb}. h1 in 32 KB XOR-swizzled LDS.
__global__ __launch_bounds__(256, 3) void mlp_fused(
    const float* __restrict__ xs,
    const unsigned short* __restrict__ w1t,   // [M][H][IN] bf16
    const float* __restrict__ b1,
    const unsigned short* __restrict__ w2t,   // [M][H][H] bf16 (n-major)
    const float* __restrict__ b2,
    const float* __restrict__ w3,             // [M][H]
    const float* __restrict__ b3,             // [M]
    float* __restrict__ out)                  // [M][B]
{
    __shared__ unsigned short h1s[64 * 256];      // 32 KB
    float* red = (float*)&h1s[0];                 // phase-3 overlay (behind barrier)

    const int bid  = blockIdx.x;
    const int m    = bid >> 6;
    const int tile = bid & 63;                    // batch tile 0..63
    const int tid  = threadIdx.x;
    const int w    = tid >> 6;
    const int lane = tid & 63;
    const int q    = lane >> 4;
    const int c16  = lane & 15;
    const int sw   = c16 & 7;

    // hoisted uniform-ish loads (latency hidden behind phase 1)
    floatx4 b1v = *(const floatx4*)(b1 + m * H_DIM + w * 64 + c16 * 4);
    floatx4 b2v = *(const floatx4*)(b2 + m * H_DIM + w * 64 + c16 * 4);
    floatx4 w3v = *(const floatx4*)(w3 + m * H_DIM + w * 64 + c16 * 4);
    const float b3v = b3[m];

    // ---------------- Phase 1: h1 = relu(x @ W1 + b1) ----------------
    const float* xrow0 = xs + ((size_t)m * BBATCH + (size_t)tile * 64) * IN_DIM;
    const unsigned short* w1p = w1t + (size_t)m * (H_DIM * IN_DIM)
                                + (w * 64 + c16 * 4) * IN_DIM + q * 8;
    const unsigned short* w2p = w2t + (size_t)m * (H_DIM * H_DIM)
                                + (w * 64 + c16 * 4) * H_DIM + q * 8;

    short8 ax[4][2];
#pragma unroll
    for (int rb = 0; rb < 4; ++rb)
#pragma unroll
        for (int kb = 0; kb < 2; ++kb) {
            const float* xp = xrow0 + (rb * 16 + c16) * IN_DIM + kb * 32 + q * 8;
            float4 v0 = *(const float4*)xp;
            float4 v1 = *(const float4*)(xp + 4);
            uint4v u;
            u[0] = pkbf(v0.x, v0.y); u[1] = pkbf(v0.z, v0.w);
            u[2] = pkbf(v1.x, v1.y); u[3] = pkbf(v1.z, v1.w);
            ax[rb][kb] = __builtin_bit_cast(short8, u);
        }

    floatx4 acc[4][4];
#pragma unroll
    for (int rb = 0; rb < 4; ++rb)
#pragma unroll
        for (int nb = 0; nb < 4; ++nb)
            acc[rb][nb] = (floatx4){0.f, 0.f, 0.f, 0.f};

    {
        short8 bw[2][4];
#pragma unroll
        for (int kb = 0; kb < 2; ++kb)
#pragma unroll
            for (int nb = 0; nb < 4; ++nb)
                bw[kb][nb] = *(const short8*)(w1p + nb * IN_DIM + kb * 32);
#pragma unroll
        for (int kb = 0; kb < 2; ++kb)
#pragma unroll
            for (int nb = 0; nb < 4; ++nb)
#pragma unroll
                for (int rb = 0; rb < 4; ++rb)
                    acc[rb][nb] = __builtin_amdgcn_mfma_f32_16x16x32_bf16(
                        ax[rb][kb], bw[kb][nb], acc[rb][nb], 0, 0, 0);
    }

    // Prefetch phase-2 B slot kb=0 NOW (h1-independent): L2 latency overlaps
    // the epilogue cvt/ds_write and the barrier drain.
    short8 bv[2][4];
#pragma unroll
    for (int nb = 0; nb < 4; ++nb)
        bv[0][nb] = *(const short8*)(w2p + nb * H_DIM);

    {   // epilogue: bias+relu+packed cvt, 8B ds_write per (rb,r), 16B-chunk XOR swizzle
#pragma unroll
        for (int rb = 0; rb < 4; ++rb)
#pragma unroll
            for (int r = 0; r < 4; ++r) {
                float v0 = fmaxf(acc[rb][0][r] + b1v[0], 0.f);
                float v1 = fmaxf(acc[rb][1][r] + b1v[1], 0.f);
                float v2 = fmaxf(acc[rb][2][r] + b1v[2], 0.f);
                float v3 = fmaxf(acc[rb][3][r] + b1v[3], 0.f);
                uint2v u2; u2[0] = pkbf(v0, v1); u2[1] = pkbf(v2, v3);
                int row = rb * 16 + q * 4 + r;
                int chunk = (w * 8 + (c16 >> 1)) ^ (row & 7);
                *(uint2v*)((char*)&h1s[0] + row * 512 + chunk * 16 + (c16 & 1) * 8) = u2;
            }
    }
    __syncthreads();

    // ---------------- Phase 2: h2 = relu(h1 @ W2 + b2); ping-pong B prefetch ----
#pragma unroll
    for (int rb = 0; rb < 4; ++rb)
#pragma unroll
        for (int nb = 0; nb < 4; ++nb)
            acc[rb][nb] = (floatx4){0.f, 0.f, 0.f, 0.f};

#pragma unroll
    for (int kb = 0; kb < 8; ++kb) {
        if (kb < 7) {                             // depth-1 in flight
#pragma unroll
            for (int nb = 0; nb < 4; ++nb)
                bv[(kb + 1) & 1][nb] = *(const short8*)(w2p + nb * H_DIM + (kb + 1) * 32);
        }
        short8 av[4];
#pragma unroll
        for (int rb = 0; rb < 4; ++rb)
            av[rb] = *(const short8*)((char*)&h1s[0] + (rb * 16 + c16) * 512
                                      + (((kb * 4 + q) ^ sw) * 16));
#pragma unroll
        for (int nb = 0; nb < 4; ++nb)
#pragma unroll
            for (int rb = 0; rb < 4; ++rb)
                acc[rb][nb] = __builtin_amdgcn_mfma_f32_16x16x32_bf16(
                    av[rb], bv[kb & 1][nb], acc[rb][nb], 0, 0, 0);
    }

    // ---------------- Phase 3: out = h2 @ W3 + b3 (OUT=1), shfl reduce ----------
    float p[4][4];
#pragma unroll
    for (int rb = 0; rb < 4; ++rb)
#pragma unroll
        for (int r = 0; r < 4; ++r) p[rb][r] = 0.f;
#pragma unroll
    for (int rb = 0; rb < 4; ++rb)
#pragma unroll
        for (int nb = 0; nb < 4; ++nb)
#pragma unroll
            for (int r = 0; r < 4; ++r) {
                float v = fmaxf(acc[rb][nb][r] + b2v[nb], 0.f);
                p[rb][r] += v * w3v[nb];
            }
#pragma unroll
    for (int off = 1; off < 16; off <<= 1)
#pragma unroll
        for (int rb = 0; rb < 4; ++rb)
#pragma unroll
            for (int r = 0; r < 4; ++r)
                p[rb][r] += __shfl_xor(p[rb][r], off);

    __syncthreads();                   // all h1s reads done -> overlay red
    if (c16 == 0) {
#pragma unroll
        for (int rb = 0; rb < 4; ++rb)
#pragma unroll
            for (int r = 0; r < 4; ++r)
                red[w * 64 + rb * 16 + q * 4 + r] = p[rb][r];
    }
    __syncthreads();
    if (tid < 64) {
        float s = red[tid] + red[64 + tid] + red[128 + tid] + red[192 + tid] + b3v;
        out[(size_t)m * BBATCH + tile * 64 + tid] = s;
    }
}

extern "C" void kernel_launch(void* const* d_in, const int* in_sizes, int n_in,
                              void* d_out, int out_size, void* d_ws, size_t ws_size,
                              hipStream_t stream) {
    const float* xs = (const float*)d_in[0];
    const float* W1 = (const float*)d_in[1];
    const float* b1 = (const float*)d_in[2];
    const float* W2 = (const float*)d_in[3];
    const float* b2 = (const float*)d_in[4];
    const float* W3 = (const float*)d_in[5];
    const float* b3 = (const float*)d_in[6];
    float* out = (float*)d_out;

    unsigned short* w1t = (unsigned short*)d_ws;                    // 2 MB
    unsigned short* w2t = w1t + (size_t)NMODELS * H_DIM * IN_DIM;   // 8.4 MB

    prep_weights<<<256 + NMODELS * 16, 256, 0, stream>>>(W1, W2, w1t, w2t);
    mlp_fused<<<NMODELS * (BBATCH / 64), 256, 0, stream>>>(xs, w1t, b1, w2t, b2, W3, b3, out);
}